// Round 2
// baseline (707.564 us; speedup 1.0000x reference)
//
#include <hip/hip_runtime.h>
#include <math.h>

#define NPIX   65536
#define HB     128
#define EPSF   1e-6f
#define NCHUNK 32
#define CHUNK_PIX 2048   /* NPIX / NCHUNK */
#define NCOMB  24        /* 2 img * 4 batch * 3 chan */

__device__ __forceinline__ float lnf(float x) {
    /* v_log_f32 is log2 */
    return __builtin_amdgcn_logf(x) * 0.69314718055994530942f;
}

/* ---------------- kernel 1: histogram accumulation ----------------
 * One block = (img, b, c, chunk of 2048 pixels).
 * 256 threads; thread t owns output sub-tile u in [tu*8, tu*8+8),
 * v in [tv*8, tv*8+8)  (tu = t>>4, tv = t&15)  -> 64 fp32 accumulators.
 * Per pixel: 256 kernel evals generated cooperatively (1/thread) into LDS,
 * then every thread does 64 FMAs. */
__global__ __launch_bounds__(256) void hist_accum(
    const float* __restrict__ pred, const float* __restrict__ tgt,
    float* __restrict__ hist, float* __restrict__ parts, int use_parts)
{
    __shared__ float sIu[256], sIv[256], sW[256];
    __shared__ float sADV[16][256];

    const int t     = threadIdx.x;
    const int chunk = blockIdx.x % NCHUNK;
    const int comb  = blockIdx.x / NCHUNK;
    const int c     = comb % 3;
    const int b     = (comb / 3) % 4;
    const int img   = comb / 12;

    const float* base = (img ? tgt : pred) + (size_t)b * 3 * NPIX;
    int c0, c1, c2;
    if      (c == 0) { c0 = 0; c1 = 1; c2 = 2; }
    else if (c == 1) { c0 = 1; c1 = 0; c2 = 2; }
    else             { c0 = 2; c1 = 0; c2 = 1; }
    const float* __restrict__ P0 = base + c0 * NPIX;
    const float* __restrict__ P1 = base + c1 * NPIX;
    const float* __restrict__ P2 = base + c2 * NPIX;

    const float mu = -3.0f + (6.0f / 127.0f) * (float)(t & 127);
    const int tu = t >> 4;
    const int tv = t & 15;
    const int duSide = (t < 128);   /* wave-uniform: waves 0,1 vs 2,3 */

    float acc[8][8];
#pragma unroll
    for (int i = 0; i < 8; ++i)
#pragma unroll
        for (int j = 0; j < 8; ++j) acc[i][j] = 0.0f;

    const int n0 = chunk * CHUNK_PIX;
    for (int p0 = n0; p0 < n0 + CHUNK_PIX; p0 += 256) {
        const int n = p0 + t;
        float x0 = P0[n], x1 = P1[n], x2 = P2[n];
        x0 = fminf(fmaxf(x0, 0.0f), 1.0f);
        x1 = fminf(fmaxf(x1, 0.0f), 1.0f);
        x2 = fminf(fmaxf(x2, 0.0f), 1.0f);
        const float l0 = lnf(x0 + EPSF);
        const float l1 = lnf(x1 + EPSF);
        const float l2 = lnf(x2 + EPSF);
        const float w  = __builtin_amdgcn_sqrtf(
            __builtin_fmaf(x0, x0, __builtin_fmaf(x1, x1, x2 * x2 + EPSF)));
        __syncthreads();             /* previous round done reading scalars */
        sIu[t] = l0 - l1;
        sIv[t] = l0 - l2;
        sW[t]  = w;
        __syncthreads();

        for (int q0 = 0; q0 < 256; q0 += 16) {
            /* generation: one inverse-quadratic eval per thread per pixel */
#pragma unroll
            for (int q = 0; q < 16; ++q) {
                const float X = duSide ? sIu[q0 + q] : sIv[q0 + q];
                const float d = (X - mu) * 50.0f;  /* 1/sigma = 50 */
                float v = __builtin_amdgcn_rcpf(__builtin_fmaf(d, d, 1.0f));
                if (duSide) v *= sW[q0 + q];       /* fold Iy into du side */
                sADV[q][t] = v;
            }
            __syncthreads();
            /* outer-product accumulate: 64 FMAs per thread per pixel */
#pragma unroll
            for (int q = 0; q < 16; ++q) {
                float av[8], dvv[8];
#pragma unroll
                for (int i = 0; i < 8; ++i) av[i]  = sADV[q][tu * 8 + i];
#pragma unroll
                for (int j = 0; j < 8; ++j) dvv[j] = sADV[q][128 + tv * 8 + j];
#pragma unroll
                for (int i = 0; i < 8; ++i)
#pragma unroll
                    for (int j = 0; j < 8; ++j)
                        acc[i][j] = __builtin_fmaf(av[i], dvv[j], acc[i][j]);
            }
            __syncthreads();
        }
    }

    if (use_parts) {
        float* p = parts + (size_t)blockIdx.x * (HB * HB);
#pragma unroll
        for (int i = 0; i < 8; ++i)
#pragma unroll
            for (int j = 0; j < 8; ++j)
                p[(tu * 8 + i) * HB + tv * 8 + j] = acc[i][j];
    } else {
        float* hp = hist + (size_t)comb * (HB * HB);
#pragma unroll
        for (int i = 0; i < 8; ++i)
#pragma unroll
            for (int j = 0; j < 8; ++j)
                atomicAdd(hp + (tu * 8 + i) * HB + tv * 8 + j, acc[i][j]);
    }
}

/* ---------------- kernel 1b: reduce per-chunk partials ---------------- */
__global__ __launch_bounds__(256) void reduce_parts(
    const float* __restrict__ parts, float* __restrict__ hist)
{
    const int i    = blockIdx.x * 256 + threadIdx.x;  /* over 24*16384 */
    const int comb = i / (HB * HB);
    const int off  = i % (HB * HB);
    const float* p = parts + ((size_t)comb * NCHUNK) * (HB * HB) + off;
    float s = 0.0f;
    for (int k = 0; k < NCHUNK; ++k) s += p[(size_t)k * (HB * HB)];
    hist[i] = s;
}

/* ---------------- kernel 2: per-(img,b) normalization sums ------------ */
__global__ __launch_bounds__(256) void norms_k(
    const float* __restrict__ hist, float* __restrict__ norms)
{
    const int ib = blockIdx.x;       /* img*4 + b, 8 blocks */
    const float* h = hist + (size_t)ib * 3 * HB * HB;
    float s = 0.0f;
    for (int i = threadIdx.x; i < 3 * HB * HB; i += 256) s += h[i];
    for (int off = 32; off > 0; off >>= 1) s += __shfl_down(s, off, 64);
    __shared__ float wsum[4];
    if ((threadIdx.x & 63) == 0) wsum[threadIdx.x >> 6] = s;
    __syncthreads();
    if (threadIdx.x == 0)
        norms[ib] = wsum[0] + wsum[1] + wsum[2] + wsum[3] + EPSF;
}

/* ---------------- kernel 3: Hellinger sum ----------------------------- */
__global__ __launch_bounds__(256) void loss_k(
    const float* __restrict__ hist, const float* __restrict__ norms,
    float* __restrict__ acc)
{
    const int i  = blockIdx.x * 256 + threadIdx.x;  /* 0..196608, exact grid */
    const int bb = i / (3 * HB * HB);
    const float rp = __builtin_amdgcn_rcpf(norms[bb]);
    const float rt = __builtin_amdgcn_rcpf(norms[4 + bb]);
    const float p  = hist[i];
    const float tt = hist[12 * HB * HB + i];
    const float d  = __builtin_amdgcn_sqrtf(tt * rt)
                   - __builtin_amdgcn_sqrtf(p * rp);
    float s = d * d;
    for (int off = 32; off > 0; off >>= 1) s += __shfl_down(s, off, 64);
    __shared__ float wsum[4];
    if ((threadIdx.x & 63) == 0) wsum[threadIdx.x >> 6] = s;
    __syncthreads();
    if (threadIdx.x == 0) atomicAdd(acc, wsum[0] + wsum[1] + wsum[2] + wsum[3]);
}

/* ---------------- kernel 4: final scalar ------------------------------ */
__global__ void final_k(const float* __restrict__ acc, float* __restrict__ out)
{
    out[0] = __builtin_amdgcn_sqrtf(acc[0]) * 0.70710678118654752440f * 0.25f;
}

extern "C" void kernel_launch(void* const* d_in, const int* in_sizes, int n_in,
                              void* d_out, int out_size, void* d_ws, size_t ws_size,
                              hipStream_t stream)
{
    const float* pred = (const float*)d_in[0];
    const float* tgt  = (const float*)d_in[1];
    float* ws = (float*)d_ws;
    float* out = (float*)d_out;

    float* hist  = ws;                /* 24*16384 = 393216 floats          */
    float* norms = ws + 393216;       /* 8 floats                          */
    float* acc   = ws + 393224;       /* 1 float (loss accumulator)        */
    float* parts = ws + 393232;       /* optional 768*16384 floats (48 MB) */

    const size_t need_parts =
        (393232 + (size_t)NCOMB * NCHUNK * HB * HB) * sizeof(float);
    const int use_parts = (ws_size >= need_parts) ? 1 : 0;

    /* zero hist + norms + acc each call (deterministic; harness poisons ws) */
    (void)hipMemsetAsync(d_ws, 0, 393232 * sizeof(float), stream);

    hist_accum<<<NCOMB * NCHUNK, 256, 0, stream>>>(pred, tgt, hist, parts,
                                                   use_parts);
    if (use_parts)
        reduce_parts<<<NCOMB * HB * HB / 256, 256, 0, stream>>>(parts, hist);
    norms_k<<<8, 256, 0, stream>>>(hist, norms);
    loss_k<<<(4 * 3 * HB * HB) / 256, 256, 0, stream>>>(hist, norms, acc);
    final_k<<<1, 1, 0, stream>>>(acc, out);
}

// Round 4
// 176.490 us; speedup vs baseline: 4.0091x; 4.0091x over previous
//
#include <hip/hip_runtime.h>

#define NPIX   65536
#define HB     128
#define EPSF   1e-6f
#define NCHUNK 32
#define KCHUNK 2048            /* pixels per block */
#define PIXB   64              /* pixels per iteration */
#define NITER  (KCHUNK / PIXB) /* 32 */
#define NCOMB  24              /* 2 img * 4 batch * 3 gemms */
#define ROWB   144             /* LDS matrix row stride: 72 f16 = 9 x 16B chunks */

typedef _Float16 half8  __attribute__((ext_vector_type(8)));
typedef __fp16   fp16x2 __attribute__((ext_vector_type(2)));
typedef float    f32x16 __attribute__((ext_vector_type(16)));

__device__ __forceinline__ unsigned pk2(float a, float b) {
    union { fp16x2 h; unsigned u; } cv;
    cv.h = __builtin_amdgcn_cvt_pkrtz(a, b);
    return cv.u;
}

/* ---------------- kernel 1: MFMA histogram GEMM ----------------
 * hist[g] for (img,b):  G = (sqrtw*K_x)^T @ (sqrtw*K_y), 128x128, K=65536.
 * g=0: (rg,rb)  g=1: (rg,gb)  g=2: (rb,gb).  Bin-flip permutations of the
 * reference channel definitions are skipped: they cancel in norms+Hellinger.
 * Block = (img,b,g,chunk): 256 thr / 4 waves, each wave a 64x64 output tile
 * (2x2 of 32x32 MFMA tiles). Per 64-px iter: gen two [128][64] f16 matrices
 * in LDS (row stride 144B -> conflict-free b128 col-writes AND row-reads),
 * then 4 K-steps x 4 mfma_f32_32x32x16_f16. */
__global__ __launch_bounds__(256) void hist_mfma(
    const float* __restrict__ pred, const float* __restrict__ tgt,
    float* __restrict__ parts, float* __restrict__ hist, int use_parts)
{
    __shared__ char  smat[2][HB * ROWB];          /* 2 x 18432 B */
    __shared__ float sXa[256], sXb[256], sRW[256];

    const int t     = threadIdx.x;
    const int chunk = blockIdx.x % NCHUNK;
    const int comb  = blockIdx.x / NCHUNK;
    const int g     = comb % 3;
    const int b     = (comb / 3) % 4;
    const int img   = comb / 12;

    const float* __restrict__ base = (img ? tgt : pred) + (size_t)b * 3 * NPIX;
    const float* __restrict__ Rp = base;
    const float* __restrict__ Gp = base + NPIX;
    const float* __restrict__ Bp = base + 2 * NPIX;

    const int   u    = t & 127;
    const int   half = t >> 7;
    const float mu50 = (float)u * (300.0f / 127.0f) - 150.0f;

    const int lane = t & 63;
    const int wave = t >> 6;
    const int ti2  = wave >> 1;   /* output row-64 group */
    const int tj2  = wave & 1;    /* output col-64 group */

    f32x16 acc[2][2];
#pragma unroll
    for (int i = 0; i < 2; ++i)
#pragma unroll
        for (int j = 0; j < 2; ++j)
#pragma unroll
            for (int r = 0; r < 16; ++r) acc[i][j][r] = 0.0f;

    const int n0 = chunk * KCHUNK;

    for (int it = 0; it < NITER; ++it) {
        /* ---- scalar phase: every 4th iter, 256 px, all threads ---- */
        if ((it & 3) == 0) {
            const int n = n0 + (it >> 2) * 256 + t;
            float r  = fminf(fmaxf(Rp[n], 0.0f), 1.0f);
            float gr = fminf(fmaxf(Gp[n], 0.0f), 1.0f);
            float bl = fminf(fmaxf(Bp[n], 0.0f), 1.0f);
            const float l2r = __builtin_amdgcn_logf(r  + EPSF);
            const float l2g = __builtin_amdgcn_logf(gr + EPSF);
            const float l2b = __builtin_amdgcn_logf(bl + EPSF);
            const float C = 34.65735902799726547086f;   /* 50 * ln2 */
            const float drg = (l2r - l2g) * C;
            const float drb = (l2r - l2b) * C;
            const float dgb = (l2g - l2b) * C;
            sXa[t] = (g == 2) ? drb : drg;
            sXb[t] = (g == 0) ? drb : dgb;
            const float s = __builtin_fmaf(r, r,
                             __builtin_fmaf(gr, gr,
                              __builtin_fmaf(bl, bl, EPSF)));
            sRW[t] = __builtin_amdgcn_sqrtf(__builtin_amdgcn_sqrtf(s));
        }
        __syncthreads();   /* scalars ready; prev iter's MFMA reads done */

        /* ---- gen phase: thread t -> bin u, pixel-half `half` ---- */
        const int pb = (it & 3) * 64 + half * 32;
#pragma unroll
        for (int side = 0; side < 2; ++side) {
            const float* __restrict__ sX = side ? sXb : sXa;
            char* mrow = smat[side] + u * ROWB + half * 64;
#pragma unroll
            for (int grp = 0; grp < 4; ++grp) {
                float v[8];
#pragma unroll
                for (int j = 0; j < 8; ++j) {
                    const int p = pb + grp * 8 + j;
                    const float d = sX[p] - mu50;
                    v[j] = __builtin_amdgcn_rcpf(__builtin_fmaf(d, d, 1.0f))
                           * sRW[p];
                }
                uint4 q;
                q.x = pk2(v[0], v[1]); q.y = pk2(v[2], v[3]);
                q.z = pk2(v[4], v[5]); q.w = pk2(v[6], v[7]);
                *reinterpret_cast<uint4*>(mrow + grp * 16) = q;
            }
        }
        __syncthreads();   /* matrices ready */

        /* ---- MFMA phase: 4 K-steps of 16 px ---- */
#pragma unroll
        for (int k0 = 0; k0 < 4; ++k0) {
            const int koff = k0 * 32 + ((lane >> 5) << 4);  /* bytes in row */
            const int r0 = ti2 * 64 + (lane & 31);
            const int c0 = tj2 * 64 + (lane & 31);
            half8 a0 = *reinterpret_cast<const half8*>(smat[0] + r0 * ROWB + koff);
            half8 a1 = *reinterpret_cast<const half8*>(smat[0] + (r0 + 32) * ROWB + koff);
            half8 b0 = *reinterpret_cast<const half8*>(smat[1] + c0 * ROWB + koff);
            half8 b1 = *reinterpret_cast<const half8*>(smat[1] + (c0 + 32) * ROWB + koff);
            acc[0][0] = __builtin_amdgcn_mfma_f32_32x32x16_f16(a0, b0, acc[0][0], 0, 0, 0);
            acc[0][1] = __builtin_amdgcn_mfma_f32_32x32x16_f16(a0, b1, acc[0][1], 0, 0, 0);
            acc[1][0] = __builtin_amdgcn_mfma_f32_32x32x16_f16(a1, b0, acc[1][0], 0, 0, 0);
            acc[1][1] = __builtin_amdgcn_mfma_f32_32x32x16_f16(a1, b1, acc[1][1], 0, 0, 0);
        }
        /* no barrier here: next iter's first __syncthreads protects smat */
    }

    /* ---- epilogue: C/D layout col=lane&31, row=(r&3)+8*(r>>2)+4*(lane>>5) */
    if (use_parts) {
        float* pp = parts + (size_t)blockIdx.x * (HB * HB);
#pragma unroll
        for (int i2 = 0; i2 < 2; ++i2)
#pragma unroll
            for (int j2 = 0; j2 < 2; ++j2) {
                const int ub = (ti2 * 2 + i2) * 32 + 4 * (lane >> 5);
                const int vc = (tj2 * 2 + j2) * 32 + (lane & 31);
#pragma unroll
                for (int r = 0; r < 16; ++r) {
                    const int urow = ub + (r & 3) + 8 * (r >> 2);
                    pp[urow * HB + vc] = acc[i2][j2][r];
                }
            }
    } else {
        float* hp = hist + (size_t)comb * (HB * HB);
#pragma unroll
        for (int i2 = 0; i2 < 2; ++i2)
#pragma unroll
            for (int j2 = 0; j2 < 2; ++j2) {
                const int ub = (ti2 * 2 + i2) * 32 + 4 * (lane >> 5);
                const int vc = (tj2 * 2 + j2) * 32 + (lane & 31);
#pragma unroll
                for (int r = 0; r < 16; ++r) {
                    const int urow = ub + (r & 3) + 8 * (r >> 2);
                    atomicAdd(hp + urow * HB + vc, acc[i2][j2][r]);
                }
            }
    }
}

/* ---------------- kernel 1b: reduce per-chunk partials ---------------- */
__global__ __launch_bounds__(256) void reduce_parts(
    const float* __restrict__ parts, float* __restrict__ hist)
{
    const int i    = blockIdx.x * 256 + threadIdx.x;  /* over 24*16384 */
    const int comb = i / (HB * HB);
    const int off  = i % (HB * HB);
    const float* p = parts + ((size_t)comb * NCHUNK) * (HB * HB) + off;
    float s = 0.0f;
    for (int k = 0; k < NCHUNK; ++k) s += p[(size_t)k * (HB * HB)];
    hist[i] = s;
}

/* ---------------- kernel 2: per-(img,b) normalization sums ------------ */
__global__ __launch_bounds__(256) void norms_k(
    const float* __restrict__ hist, float* __restrict__ norms)
{
    const int ib = blockIdx.x;       /* img*4 + b, 8 blocks */
    const float* h = hist + (size_t)ib * 3 * HB * HB;
    float s = 0.0f;
    for (int i = threadIdx.x; i < 3 * HB * HB; i += 256) s += h[i];
    for (int off = 32; off > 0; off >>= 1) s += __shfl_down(s, off, 64);
    __shared__ float wsum[4];
    if ((threadIdx.x & 63) == 0) wsum[threadIdx.x >> 6] = s;
    __syncthreads();
    if (threadIdx.x == 0)
        norms[ib] = wsum[0] + wsum[1] + wsum[2] + wsum[3] + EPSF;
}

/* ---------------- kernel 3: Hellinger sum ----------------------------- */
__global__ __launch_bounds__(256) void loss_k(
    const float* __restrict__ hist, const float* __restrict__ norms,
    float* __restrict__ acc)
{
    const int i  = blockIdx.x * 256 + threadIdx.x;  /* 0..196608, exact grid */
    const int bb = i / (3 * HB * HB);
    const float rp = __builtin_amdgcn_rcpf(norms[bb]);
    const float rt = __builtin_amdgcn_rcpf(norms[4 + bb]);
    const float p  = hist[i];
    const float tt = hist[12 * HB * HB + i];
    const float d  = __builtin_amdgcn_sqrtf(tt * rt)
                   - __builtin_amdgcn_sqrtf(p * rp);
    float s = d * d;
    for (int off = 32; off > 0; off >>= 1) s += __shfl_down(s, off, 64);
    __shared__ float wsum[4];
    if ((threadIdx.x & 63) == 0) wsum[threadIdx.x >> 6] = s;
    __syncthreads();
    if (threadIdx.x == 0) atomicAdd(acc, wsum[0] + wsum[1] + wsum[2] + wsum[3]);
}

/* ---------------- kernel 4: final scalar ------------------------------ */
__global__ void final_k(const float* __restrict__ acc, float* __restrict__ out)
{
    out[0] = __builtin_amdgcn_sqrtf(acc[0]) * 0.70710678118654752440f * 0.25f;
}

extern "C" void kernel_launch(void* const* d_in, const int* in_sizes, int n_in,
                              void* d_out, int out_size, void* d_ws, size_t ws_size,
                              hipStream_t stream)
{
    const float* pred = (const float*)d_in[0];
    const float* tgt  = (const float*)d_in[1];
    float* ws  = (float*)d_ws;
    float* out = (float*)d_out;

    float* hist  = ws;                /* 24*16384 = 393216 floats          */
    float* norms = ws + 393216;       /* 8 floats                          */
    float* acc   = ws + 393224;       /* 1 float (loss accumulator)        */
    float* parts = ws + 393232;       /* 768*16384 floats (50.3 MB)        */

    const size_t need_parts =
        (393232 + (size_t)NCOMB * NCHUNK * HB * HB) * sizeof(float);
    const int use_parts = (ws_size >= need_parts) ? 1 : 0;

    if (use_parts) {
        (void)hipMemsetAsync(acc, 0, 16, stream);           /* acc only */
    } else {
        (void)hipMemsetAsync(d_ws, 0, 393232 * sizeof(float), stream);
    }

    hist_mfma<<<NCOMB * NCHUNK, 256, 0, stream>>>(pred, tgt, parts, hist,
                                                  use_parts);
    if (use_parts)
        reduce_parts<<<NCOMB * HB * HB / 256, 256, 0, stream>>>(parts, hist);
    norms_k<<<8, 256, 0, stream>>>(hist, norms);
    loss_k<<<(4 * 3 * HB * HB) / 256, 256, 0, stream>>>(hist, norms, acc);
    final_k<<<1, 1, 0, stream>>>(acc, out);
}

// Round 5
// 146.913 us; speedup vs baseline: 4.8162x; 1.2013x over previous
//
#include <hip/hip_runtime.h>

#define NPIX   65536
#define HB     128
#define EPSF   1e-6f
#define NCOMB  24              /* (img*4+b)*3+g */
#define ROWB   144             /* LDS row stride: 72 f16 = 9 x 16B chunks */
#define PPB    49152           /* parts floats per block: 3*128*128 */

typedef _Float16 half8  __attribute__((ext_vector_type(8)));
typedef __fp16   fp16x2 __attribute__((ext_vector_type(2)));
typedef float    f32x16 __attribute__((ext_vector_type(16)));

__device__ __forceinline__ unsigned pk2(float a, float b) {
    union { fp16x2 h; unsigned u; } cv;
    cv.h = __builtin_amdgcn_cvt_pkrtz(a, b);
    return cv.u;
}

/* ---------------- kernel 1: shared-field MFMA histogram GEMM ----------
 * Per (img,b): 3 fields d_rg, d_rb, d_gb -> 3 K-matrices (sqrt(w) folded
 * into each).  G0=K_rg^T K_rb, G1=K_rg^T K_gb, G2=K_rb^T K_gb.  Bin-flip
 * permutations of the reference channel defs cancel in norms+Hellinger.
 * Block = (img,b,chunk), 256 thr / 4 waves.  Per 64-px iter: gen THREE
 * [128][64] f16 matrices in LDS (row stride 144B, conflict-free), then
 * each wave does its 64x64 tile of all 3 GEMMs: 4 k-steps x 12 MFMA.
 * Gen work per GEMM is halved vs one-GEMM-per-block. */
__global__ __launch_bounds__(256, 2) void hist_mfma(
    const float* __restrict__ pred, const float* __restrict__ tgt,
    float* __restrict__ parts, int nchunk)
{
    __shared__ char  smat[3][HB * ROWB];          /* 3 x 18432 B */
    __shared__ float sD[3][256], sRW[256];

    const int t     = threadIdx.x;
    const int chunk = blockIdx.x % nchunk;
    const int ib    = blockIdx.x / nchunk;        /* img*4 + b */
    const int b     = ib & 3;
    const int img   = ib >> 2;
    const int kchunk = NPIX / nchunk;
    const int niter  = kchunk >> 6;               /* 64 px per iter */

    const float* __restrict__ base = (img ? tgt : pred) + (size_t)b * 3 * NPIX;
    const float* __restrict__ Rp = base;
    const float* __restrict__ Gp = base + NPIX;
    const float* __restrict__ Bp = base + 2 * NPIX;

    const int   u    = t & 127;
    const int   half = t >> 7;
    const float mu50 = (float)u * (300.0f / 127.0f) - 150.0f;

    const int lane = t & 63;
    const int wave = t >> 6;
    const int ti2  = wave >> 1;   /* output row-64 group */
    const int tj2  = wave & 1;    /* output col-64 group */

    f32x16 acc[3][2][2];
#pragma unroll
    for (int g = 0; g < 3; ++g)
#pragma unroll
        for (int i = 0; i < 2; ++i)
#pragma unroll
            for (int j = 0; j < 2; ++j)
#pragma unroll
                for (int r = 0; r < 16; ++r) acc[g][i][j][r] = 0.0f;

    const int n0 = chunk * kchunk;

    for (int it = 0; it < niter; ++it) {
        /* ---- scalar phase: every 4th iter, 256 px, all threads ---- */
        if ((it & 3) == 0) {
            const int n = n0 + (it >> 2) * 256 + t;
            float r  = fminf(fmaxf(Rp[n], 0.0f), 1.0f);
            float gr = fminf(fmaxf(Gp[n], 0.0f), 1.0f);
            float bl = fminf(fmaxf(Bp[n], 0.0f), 1.0f);
            const float l2r = __builtin_amdgcn_logf(r  + EPSF);
            const float l2g = __builtin_amdgcn_logf(gr + EPSF);
            const float l2b = __builtin_amdgcn_logf(bl + EPSF);
            const float C = 34.65735902799726547086f;   /* 50 * ln2 */
            sD[0][t] = (l2r - l2g) * C;   /* d_rg */
            sD[1][t] = (l2r - l2b) * C;   /* d_rb */
            sD[2][t] = (l2g - l2b) * C;   /* d_gb */
            const float s = __builtin_fmaf(r, r,
                             __builtin_fmaf(gr, gr,
                              __builtin_fmaf(bl, bl, EPSF)));
            sRW[t] = __builtin_amdgcn_sqrtf(__builtin_amdgcn_sqrtf(s));
        }
        __syncthreads();   /* scalars ready; prev iter's MFMA reads done */

        /* ---- gen phase: thread t -> bin u, pixel-half `half`, 3 sides - */
        const int pb = (it & 3) * 64 + half * 32;
#pragma unroll
        for (int side = 0; side < 3; ++side) {
            const float* __restrict__ sX = sD[side];
            char* mrow = smat[side] + u * ROWB + half * 64;
#pragma unroll
            for (int grp = 0; grp < 4; ++grp) {
                float v[8];
#pragma unroll
                for (int j = 0; j < 8; ++j) {
                    const int p = pb + grp * 8 + j;
                    const float d = sX[p] - mu50;
                    v[j] = __builtin_amdgcn_rcpf(__builtin_fmaf(d, d, 1.0f))
                           * sRW[p];
                }
                uint4 q;
                q.x = pk2(v[0], v[1]); q.y = pk2(v[2], v[3]);
                q.z = pk2(v[4], v[5]); q.w = pk2(v[6], v[7]);
                *reinterpret_cast<uint4*>(mrow + grp * 16) = q;
            }
        }
        __syncthreads();   /* matrices ready */

        /* ---- MFMA phase: 4 K-steps x 12 MFMA ---- */
#pragma unroll
        for (int k0 = 0; k0 < 4; ++k0) {
            const int koff = k0 * 32 + ((lane >> 5) << 4);  /* bytes in row */
            const int r0 = ti2 * 64 + (lane & 31);
            const int c0 = tj2 * 64 + (lane & 31);
            /* K_rg rows (A of G0,G1) */
            half8 a0 = *reinterpret_cast<const half8*>(smat[0] + r0 * ROWB + koff);
            half8 a1 = *reinterpret_cast<const half8*>(smat[0] + (r0 + 32) * ROWB + koff);
            /* K_rb cols (B of G0) */
            half8 p0 = *reinterpret_cast<const half8*>(smat[1] + c0 * ROWB + koff);
            half8 p1 = *reinterpret_cast<const half8*>(smat[1] + (c0 + 32) * ROWB + koff);
            acc[0][0][0] = __builtin_amdgcn_mfma_f32_32x32x16_f16(a0, p0, acc[0][0][0], 0, 0, 0);
            acc[0][0][1] = __builtin_amdgcn_mfma_f32_32x32x16_f16(a0, p1, acc[0][0][1], 0, 0, 0);
            acc[0][1][0] = __builtin_amdgcn_mfma_f32_32x32x16_f16(a1, p0, acc[0][1][0], 0, 0, 0);
            acc[0][1][1] = __builtin_amdgcn_mfma_f32_32x32x16_f16(a1, p1, acc[0][1][1], 0, 0, 0);
            /* K_gb cols (B of G1,G2) */
            half8 q0 = *reinterpret_cast<const half8*>(smat[2] + c0 * ROWB + koff);
            half8 q1 = *reinterpret_cast<const half8*>(smat[2] + (c0 + 32) * ROWB + koff);
            acc[1][0][0] = __builtin_amdgcn_mfma_f32_32x32x16_f16(a0, q0, acc[1][0][0], 0, 0, 0);
            acc[1][0][1] = __builtin_amdgcn_mfma_f32_32x32x16_f16(a0, q1, acc[1][0][1], 0, 0, 0);
            acc[1][1][0] = __builtin_amdgcn_mfma_f32_32x32x16_f16(a1, q0, acc[1][1][0], 0, 0, 0);
            acc[1][1][1] = __builtin_amdgcn_mfma_f32_32x32x16_f16(a1, q1, acc[1][1][1], 0, 0, 0);
            /* K_rb rows (A of G2) */
            half8 b0 = *reinterpret_cast<const half8*>(smat[1] + r0 * ROWB + koff);
            half8 b1 = *reinterpret_cast<const half8*>(smat[1] + (r0 + 32) * ROWB + koff);
            acc[2][0][0] = __builtin_amdgcn_mfma_f32_32x32x16_f16(b0, q0, acc[2][0][0], 0, 0, 0);
            acc[2][0][1] = __builtin_amdgcn_mfma_f32_32x32x16_f16(b0, q1, acc[2][0][1], 0, 0, 0);
            acc[2][1][0] = __builtin_amdgcn_mfma_f32_32x32x16_f16(b1, q0, acc[2][1][0], 0, 0, 0);
            acc[2][1][1] = __builtin_amdgcn_mfma_f32_32x32x16_f16(b1, q1, acc[2][1][1], 0, 0, 0);
        }
        /* no barrier: next iter's first __syncthreads protects smat */
    }

    /* ---- epilogue: C/D layout col=lane&31, row=(r&3)+8*(r>>2)+4*(lane>>5) */
    float* pb0 = parts + (size_t)blockIdx.x * PPB;
#pragma unroll
    for (int g = 0; g < 3; ++g) {
        float* pp = pb0 + g * (HB * HB);
#pragma unroll
        for (int i2 = 0; i2 < 2; ++i2)
#pragma unroll
            for (int j2 = 0; j2 < 2; ++j2) {
                const int ub = (ti2 * 2 + i2) * 32 + 4 * (lane >> 5);
                const int vc = (tj2 * 2 + j2) * 32 + (lane & 31);
#pragma unroll
                for (int r = 0; r < 16; ++r) {
                    const int urow = ub + (r & 3) + 8 * (r >> 2);
                    pp[urow * HB + vc] = acc[g][i2][j2][r];
                }
            }
    }
}

/* ------- kernel 2: reduce per-chunk partials + fused norm sums -------- */
__global__ __launch_bounds__(256) void reduce_norms(
    const float* __restrict__ parts, float* __restrict__ hist,
    float* __restrict__ norms, int nchunk)
{
    const int i    = blockIdx.x * 256 + threadIdx.x;  /* over 24*16384 */
    const int comb = i >> 14;            /* ib*3 + g  (uniform per block) */
    const int off  = i & 16383;
    const int ib   = comb / 3;
    const int g    = comb % 3;
    const float* p = parts + (size_t)(ib * nchunk) * PPB + g * (HB * HB) + off;
    float s = 0.0f;
    for (int k = 0; k < nchunk; ++k) s += p[(size_t)k * PPB];
    hist[i] = s;
    /* block partial sum -> norms[ib] (all threads in block share ib) */
    for (int o = 32; o > 0; o >>= 1) s += __shfl_down(s, o, 64);
    __shared__ float wsum[4];
    if ((threadIdx.x & 63) == 0) wsum[threadIdx.x >> 6] = s;
    __syncthreads();
    if (threadIdx.x == 0)
        atomicAdd(&norms[ib], wsum[0] + wsum[1] + wsum[2] + wsum[3]);
}

/* ---------------- kernel 3: Hellinger sum ----------------------------- */
__global__ __launch_bounds__(256) void loss_k(
    const float* __restrict__ hist, const float* __restrict__ norms,
    float* __restrict__ acc)
{
    const int i  = blockIdx.x * 256 + threadIdx.x;  /* 0..196608, exact grid */
    const int bb = i / (3 * HB * HB);
    const float rp = __builtin_amdgcn_rcpf(norms[bb] + EPSF);
    const float rt = __builtin_amdgcn_rcpf(norms[4 + bb] + EPSF);
    const float p  = hist[i];
    const float tt = hist[12 * HB * HB + i];
    const float d  = __builtin_amdgcn_sqrtf(tt * rt)
                   - __builtin_amdgcn_sqrtf(p * rp);
    float s = d * d;
    for (int o = 32; o > 0; o >>= 1) s += __shfl_down(s, o, 64);
    __shared__ float wsum[4];
    if ((threadIdx.x & 63) == 0) wsum[threadIdx.x >> 6] = s;
    __syncthreads();
    if (threadIdx.x == 0) atomicAdd(acc, wsum[0] + wsum[1] + wsum[2] + wsum[3]);
}

/* ---------------- kernel 4: final scalar ------------------------------ */
__global__ void final_k(const float* __restrict__ acc, float* __restrict__ out)
{
    out[0] = __builtin_amdgcn_sqrtf(acc[0]) * 0.70710678118654752440f * 0.25f;
}

extern "C" void kernel_launch(void* const* d_in, const int* in_sizes, int n_in,
                              void* d_out, int out_size, void* d_ws, size_t ws_size,
                              hipStream_t stream)
{
    const float* pred = (const float*)d_in[0];
    const float* tgt  = (const float*)d_in[1];
    float* ws  = (float*)d_ws;
    float* out = (float*)d_out;

    float* hist  = ws;                /* 24*16384 = 393216 floats          */
    float* norms = ws + 393216;       /* 8 floats                          */
    float* acc   = ws + 393224;       /* 1 float                           */
    float* parts = ws + 393232;       /* 8*nchunk*PPB floats               */

    /* pick the largest chunk count whose parts buffer fits the workspace */
    int nchunk = 64;
    for (;;) {
        const size_t need =
            (393232 + (size_t)8 * nchunk * PPB) * sizeof(float);
        if (need <= ws_size || nchunk == 1) break;
        nchunk >>= (nchunk == 64) ? 1 : 2;   /* 64 -> 32 -> 8 -> 2 -> 1 */
    }

    (void)hipMemsetAsync(norms, 0, 9 * sizeof(float), stream);  /* norms+acc */

    hist_mfma<<<8 * nchunk, 256, 0, stream>>>(pred, tgt, parts, nchunk);
    reduce_norms<<<NCOMB * HB * HB / 256, 256, 0, stream>>>(parts, hist,
                                                            norms, nchunk);
    loss_k<<<(4 * 3 * HB * HB) / 256, 256, 0, stream>>>(hist, norms, acc);
    final_k<<<1, 1, 0, stream>>>(acc, out);
}

// Round 6
// 142.708 us; speedup vs baseline: 4.9581x; 1.0295x over previous
//
#include <hip/hip_runtime.h>

#define NPIX   65536
#define HB     128
#define EPSF   1e-6f
#define NCOMB  24              /* (img*4+b)*3+g */
#define ROWB   144             /* LDS row stride: 72 f16 = 9 x 16B chunks */
#define PPB    49152           /* parts floats per block: 3*128*128 */

typedef _Float16 half8  __attribute__((ext_vector_type(8)));
typedef __fp16   fp16x2 __attribute__((ext_vector_type(2)));
typedef float    f32x16 __attribute__((ext_vector_type(16)));

__device__ __forceinline__ unsigned pk2(float a, float b) {
    union { fp16x2 h; unsigned u; } cv;
    cv.h = __builtin_amdgcn_cvt_pkrtz(a, b);
    return cv.u;
}
__device__ __forceinline__ float rl(float x, int i) {
    return __int_as_float(__builtin_amdgcn_readlane(__float_as_int(x), i));
}

/* ---------------- kernel 1: shared-field MFMA histogram GEMM ----------
 * Per (img,b): 3 fields d_rg, d_rb, d_gb -> 3 K-matrices (sqrt(w) folded).
 * G0=K_rg^T K_rb, G1=K_rg^T K_gb, G2=K_rb^T K_gb (bin-flips cancel in
 * norms+Hellinger).  Block=(img,b,chunk), 256 thr / 4 waves, 2 blocks/CU.
 * Per 64-px iter:
 *   scalar: lane l computes pixel (it*64+l)'s d0,d1,d2,rw in registers
 *           (before the barrier -> overlaps prev iter's MFMA);
 *   gen:    wave=(pxhalf,binhalf); lane owns bin-row, scalars broadcast
 *           via v_readlane (ZERO LDS reads); 12 b128 LDS writes/wave;
 *   mfma:   4 k-steps x 12 mfma_f32_32x32x16_f16 (64x64 tile x 3 GEMMs).
 * LDS row stride 144B keeps both writes and reads bank-conflict-free. */
__global__ __launch_bounds__(256, 2) void hist_mfma(
    const float* __restrict__ pred, const float* __restrict__ tgt,
    float* __restrict__ parts, int nchunk)
{
    __shared__ char smat[3][HB * ROWB];           /* 3 x 18432 B */

    const int t     = threadIdx.x;
    const int lane  = t & 63;
    const int wave  = t >> 6;
    const int chunk = blockIdx.x % nchunk;
    const int ib    = blockIdx.x / nchunk;        /* img*4 + b */
    const int b     = ib & 3;
    const int img   = ib >> 2;
    const int kchunk = NPIX / nchunk;
    const int niter  = kchunk >> 6;               /* 64 px per iter */

    const float* __restrict__ base = (img ? tgt : pred) + (size_t)b * 3 * NPIX;
    const float* __restrict__ Rp = base;
    const float* __restrict__ Gp = base + NPIX;
    const float* __restrict__ Bp = base + 2 * NPIX;

    /* gen role */
    const int   binhalf = wave & 1;
    const int   mybin   = binhalf * 64 + lane;
    const float mu50    = (float)mybin * (300.0f / 127.0f) - 150.0f;
    const int   pxbase  = __builtin_amdgcn_readfirstlane((wave >> 1) * 32);
    const int   pxoff   = (wave >> 1) * 64;       /* byte offset in row */

    /* mfma role */
    const int ti2 = wave >> 1;
    const int tj2 = wave & 1;

    f32x16 acc[3][2][2];
#pragma unroll
    for (int g = 0; g < 3; ++g)
#pragma unroll
        for (int i = 0; i < 2; ++i)
#pragma unroll
            for (int j = 0; j < 2; ++j)
#pragma unroll
                for (int r = 0; r < 16; ++r) acc[g][i][j][r] = 0.0f;

    const int n0 = chunk * kchunk;

    for (int it = 0; it < niter; ++it) {
        /* ---- per-lane pixel scalars (overlaps prev iter's MFMA) ---- */
        const int n = n0 + it * 64 + lane;
        float r  = fminf(fmaxf(Rp[n], 0.0f), 1.0f);
        float gr = fminf(fmaxf(Gp[n], 0.0f), 1.0f);
        float bl = fminf(fmaxf(Bp[n], 0.0f), 1.0f);
        const float l2r = __builtin_amdgcn_logf(r  + EPSF);
        const float l2g = __builtin_amdgcn_logf(gr + EPSF);
        const float l2b = __builtin_amdgcn_logf(bl + EPSF);
        const float C = 34.65735902799726547086f;   /* 50 * ln2 */
        float dd[3];
        dd[0] = (l2r - l2g) * C;   /* d_rg */
        dd[1] = (l2r - l2b) * C;   /* d_rb */
        dd[2] = (l2g - l2b) * C;   /* d_gb */
        const float s = __builtin_fmaf(r, r,
                         __builtin_fmaf(gr, gr,
                          __builtin_fmaf(bl, bl, EPSF)));
        const float rw = __builtin_amdgcn_sqrtf(__builtin_amdgcn_sqrtf(s));

        __syncthreads();   /* prev iter's MFMA done reading smat */

        /* ---- gen: readlane broadcasts, accumulate rows in regs ---- */
#pragma unroll
        for (int mat = 0; mat < 3; ++mat) {
            unsigned pk[16];
#pragma unroll
            for (int jj = 0; jj < 16; ++jj) {
                const float s0 = rl(dd[mat], pxbase + 2 * jj);
                const float w0 = rl(rw,      pxbase + 2 * jj);
                const float s1 = rl(dd[mat], pxbase + 2 * jj + 1);
                const float w1 = rl(rw,      pxbase + 2 * jj + 1);
                const float e0 = s0 - mu50;
                const float e1 = s1 - mu50;
                const float v0 = __builtin_amdgcn_rcpf(
                                     __builtin_fmaf(e0, e0, 1.0f)) * w0;
                const float v1 = __builtin_amdgcn_rcpf(
                                     __builtin_fmaf(e1, e1, 1.0f)) * w1;
                pk[jj] = pk2(v0, v1);
            }
            char* rowp = smat[mat] + mybin * ROWB + pxoff;
            uint4 q0; q0.x = pk[0];  q0.y = pk[1];  q0.z = pk[2];  q0.w = pk[3];
            uint4 q1; q1.x = pk[4];  q1.y = pk[5];  q1.z = pk[6];  q1.w = pk[7];
            uint4 q2; q2.x = pk[8];  q2.y = pk[9];  q2.z = pk[10]; q2.w = pk[11];
            uint4 q3; q3.x = pk[12]; q3.y = pk[13]; q3.z = pk[14]; q3.w = pk[15];
            *reinterpret_cast<uint4*>(rowp)      = q0;
            *reinterpret_cast<uint4*>(rowp + 16) = q1;
            *reinterpret_cast<uint4*>(rowp + 32) = q2;
            *reinterpret_cast<uint4*>(rowp + 48) = q3;
        }
        __syncthreads();   /* matrices ready */

        /* ---- MFMA phase: 4 K-steps x 12 MFMA ---- */
#pragma unroll
        for (int k0 = 0; k0 < 4; ++k0) {
            const int koff = k0 * 32 + ((lane >> 5) << 4);  /* bytes in row */
            const int r0 = ti2 * 64 + (lane & 31);
            const int c0 = tj2 * 64 + (lane & 31);
            /* K_rg rows (A of G0,G1) */
            half8 a0 = *reinterpret_cast<const half8*>(smat[0] + r0 * ROWB + koff);
            half8 a1 = *reinterpret_cast<const half8*>(smat[0] + (r0 + 32) * ROWB + koff);
            /* K_rb cols (B of G0) */
            half8 p0 = *reinterpret_cast<const half8*>(smat[1] + c0 * ROWB + koff);
            half8 p1 = *reinterpret_cast<const half8*>(smat[1] + (c0 + 32) * ROWB + koff);
            acc[0][0][0] = __builtin_amdgcn_mfma_f32_32x32x16_f16(a0, p0, acc[0][0][0], 0, 0, 0);
            acc[0][0][1] = __builtin_amdgcn_mfma_f32_32x32x16_f16(a0, p1, acc[0][0][1], 0, 0, 0);
            acc[0][1][0] = __builtin_amdgcn_mfma_f32_32x32x16_f16(a1, p0, acc[0][1][0], 0, 0, 0);
            acc[0][1][1] = __builtin_amdgcn_mfma_f32_32x32x16_f16(a1, p1, acc[0][1][1], 0, 0, 0);
            /* K_gb cols (B of G1,G2) */
            half8 q0 = *reinterpret_cast<const half8*>(smat[2] + c0 * ROWB + koff);
            half8 q1 = *reinterpret_cast<const half8*>(smat[2] + (c0 + 32) * ROWB + koff);
            acc[1][0][0] = __builtin_amdgcn_mfma_f32_32x32x16_f16(a0, q0, acc[1][0][0], 0, 0, 0);
            acc[1][0][1] = __builtin_amdgcn_mfma_f32_32x32x16_f16(a0, q1, acc[1][0][1], 0, 0, 0);
            acc[1][1][0] = __builtin_amdgcn_mfma_f32_32x32x16_f16(a1, q0, acc[1][1][0], 0, 0, 0);
            acc[1][1][1] = __builtin_amdgcn_mfma_f32_32x32x16_f16(a1, q1, acc[1][1][1], 0, 0, 0);
            /* K_rb rows (A of G2) */
            half8 b0 = *reinterpret_cast<const half8*>(smat[1] + r0 * ROWB + koff);
            half8 b1 = *reinterpret_cast<const half8*>(smat[1] + (r0 + 32) * ROWB + koff);
            acc[2][0][0] = __builtin_amdgcn_mfma_f32_32x32x16_f16(b0, q0, acc[2][0][0], 0, 0, 0);
            acc[2][0][1] = __builtin_amdgcn_mfma_f32_32x32x16_f16(b0, q1, acc[2][0][1], 0, 0, 0);
            acc[2][1][0] = __builtin_amdgcn_mfma_f32_32x32x16_f16(b1, q0, acc[2][1][0], 0, 0, 0);
            acc[2][1][1] = __builtin_amdgcn_mfma_f32_32x32x16_f16(b1, q1, acc[2][1][1], 0, 0, 0);
        }
        /* no barrier: next iter's first __syncthreads protects smat */
    }

    /* ---- epilogue: C/D layout col=lane&31, row=(r&3)+8*(r>>2)+4*(lane>>5) */
    float* pb0 = parts + (size_t)blockIdx.x * PPB;
#pragma unroll
    for (int g = 0; g < 3; ++g) {
        float* pp = pb0 + g * (HB * HB);
#pragma unroll
        for (int i2 = 0; i2 < 2; ++i2)
#pragma unroll
            for (int j2 = 0; j2 < 2; ++j2) {
                const int ub = (ti2 * 2 + i2) * 32 + 4 * (lane >> 5);
                const int vc = (tj2 * 2 + j2) * 32 + (lane & 31);
#pragma unroll
                for (int r = 0; r < 16; ++r) {
                    const int urow = ub + (r & 3) + 8 * (r >> 2);
                    pp[urow * HB + vc] = acc[g][i2][j2][r];
                }
            }
    }
}

/* ------- kernel 2: reduce per-chunk partials + fused norm sums -------- */
__global__ __launch_bounds__(256) void reduce_norms(
    const float* __restrict__ parts, float* __restrict__ hist,
    float* __restrict__ norms, int nchunk)
{
    const int i    = blockIdx.x * 256 + threadIdx.x;  /* over 24*16384 */
    const int comb = i >> 14;            /* ib*3 + g  (uniform per block) */
    const int off  = i & 16383;
    const int ib   = comb / 3;
    const int g    = comb % 3;
    const float* p = parts + (size_t)(ib * nchunk) * PPB + g * (HB * HB) + off;
    float s = 0.0f;
    for (int k = 0; k < nchunk; ++k) s += p[(size_t)k * PPB];
    hist[i] = s;
    /* block partial sum -> norms[ib] (all threads in block share ib) */
    for (int o = 32; o > 0; o >>= 1) s += __shfl_down(s, o, 64);
    __shared__ float wsum[4];
    if ((threadIdx.x & 63) == 0) wsum[threadIdx.x >> 6] = s;
    __syncthreads();
    if (threadIdx.x == 0)
        atomicAdd(&norms[ib], wsum[0] + wsum[1] + wsum[2] + wsum[3]);
}

/* ---------------- kernel 3: Hellinger sum ----------------------------- */
__global__ __launch_bounds__(256) void loss_k(
    const float* __restrict__ hist, const float* __restrict__ norms,
    float* __restrict__ acc)
{
    const int i  = blockIdx.x * 256 + threadIdx.x;  /* 0..196608, exact grid */
    const int bb = i / (3 * HB * HB);
    const float rp = __builtin_amdgcn_rcpf(norms[bb] + EPSF);
    const float rt = __builtin_amdgcn_rcpf(norms[4 + bb] + EPSF);
    const float p  = hist[i];
    const float tt = hist[12 * HB * HB + i];
    const float d  = __builtin_amdgcn_sqrtf(tt * rt)
                   - __builtin_amdgcn_sqrtf(p * rp);
    float s = d * d;
    for (int o = 32; o > 0; o >>= 1) s += __shfl_down(s, o, 64);
    __shared__ float wsum[4];
    if ((threadIdx.x & 63) == 0) wsum[threadIdx.x >> 6] = s;
    __syncthreads();
    if (threadIdx.x == 0) atomicAdd(acc, wsum[0] + wsum[1] + wsum[2] + wsum[3]);
}

/* ---------------- kernel 4: final scalar ------------------------------ */
__global__ void final_k(const float* __restrict__ acc, float* __restrict__ out)
{
    out[0] = __builtin_amdgcn_sqrtf(acc[0]) * 0.70710678118654752440f * 0.25f;
}

extern "C" void kernel_launch(void* const* d_in, const int* in_sizes, int n_in,
                              void* d_out, int out_size, void* d_ws, size_t ws_size,
                              hipStream_t stream)
{
    const float* pred = (const float*)d_in[0];
    const float* tgt  = (const float*)d_in[1];
    float* ws  = (float*)d_ws;
    float* out = (float*)d_out;

    float* hist  = ws;                /* 24*16384 = 393216 floats          */
    float* norms = ws + 393216;       /* 8 floats                          */
    float* acc   = ws + 393224;       /* 1 float                           */
    float* parts = ws + 393232;       /* 8*nchunk*PPB floats               */

    /* pick the largest chunk count whose parts buffer fits the workspace */
    int nchunk = 64;
    for (;;) {
        const size_t need =
            (393232 + (size_t)8 * nchunk * PPB) * sizeof(float);
        if (need <= ws_size || nchunk == 1) break;
        nchunk >>= (nchunk == 64) ? 1 : 2;   /* 64 -> 32 -> 8 -> 2 -> 1 */
    }

    (void)hipMemsetAsync(norms, 0, 9 * sizeof(float), stream);  /* norms+acc */

    hist_mfma<<<8 * nchunk, 256, 0, stream>>>(pred, tgt, parts, nchunk);
    reduce_norms<<<NCOMB * HB * HB / 256, 256, 0, stream>>>(parts, hist,
                                                            norms, nchunk);
    loss_k<<<(4 * 3 * HB * HB) / 256, 256, 0, stream>>>(hist, norms, acc);
    final_k<<<1, 1, 0, stream>>>(acc, out);
}

// Round 7
// 135.266 us; speedup vs baseline: 5.2309x; 1.0550x over previous
//
#include <hip/hip_runtime.h>

#define NPIX   65536
#define HB     128
#define EPSF   1e-6f
#define NCOMB  24              /* (img*4+b)*3+g */
#define ROWB   80              /* 32 px * 2B = 64B data + 16B pad (5 x 16B) */
#define MATB   (HB * ROWB)     /* 10240 B per matrix */
#define BUFB   (3 * MATB)      /* 30720 B per buffer set */
#define PPB    49152           /* parts floats per block: 3*128*128 */

typedef _Float16 half8  __attribute__((ext_vector_type(8)));
typedef __fp16   fp16x2 __attribute__((ext_vector_type(2)));
typedef float    f32x16 __attribute__((ext_vector_type(16)));
typedef float    f32x2  __attribute__((ext_vector_type(2)));

__device__ __forceinline__ unsigned pk2(float a, float b) {
    union { fp16x2 h; unsigned u; } cv;
    cv.h = __builtin_amdgcn_cvt_pkrtz(a, b);
    return cv.u;
}

/* ---------------- kernel 1: pipelined shared-field MFMA histogram -----
 * Per (img,b): 3 fields d_rg, d_rb, d_gb -> 3 K-matrices (sqrt(w) folded).
 * G0=K_rg^T K_rb, G1=K_rg^T K_gb, G2=K_rb^T K_gb (bin-flips cancel in
 * norms+Hellinger).  Block=(img,b,chunk), 256 thr / 4 waves, 2 blocks/CU.
 * 32-px regions, double-buffered LDS, ONE barrier per region:
 *   body = { scalars[r+1]; prefetch loads[r+2]; gen[r+1]->buf(~p)
 *            || MFMA[r]<-buf(p) } ; barrier
 * Gen: lane owns px pair (2i,2i+1) (lane&15) and a bin-row quad (lane>>4);
 * scalars lane-local (redundant x4 across quads, L1-broadcast loads),
 * mu per-lane register, single vaddr + immediate ds_write offsets.
 * ROWB=80 -> conflict-free b128 MFMA reads (row*20 mod 32, period 8). */
__global__ __launch_bounds__(256, 2) void hist_mfma(
    const float* __restrict__ pred, const float* __restrict__ tgt,
    float* __restrict__ parts, int nchunk)
{
    __shared__ char smat[2 * BUFB];               /* 61440 B */

    const int t    = threadIdx.x;
    const int lane = t & 63;
    const int wave = t >> 6;
    const int chunk = blockIdx.x % nchunk;
    const int ib    = blockIdx.x / nchunk;        /* img*4 + b */
    const int b     = ib & 3;
    const int img   = ib >> 2;
    const int kchunk = NPIX / nchunk;
    const int nreg   = kchunk >> 5;               /* 32-px regions, even */

    const float* __restrict__ base = (img ? tgt : pred) + (size_t)b * 3 * NPIX;
    const float* __restrict__ Rp = base;
    const float* __restrict__ Gp = base + NPIX;
    const float* __restrict__ Bp = base + 2 * NPIX;

    /* gen role */
    const int   i16     = lane & 15;              /* px pair index */
    const int   r4      = lane >> 4;              /* row within 16-group */
    const int   rowbase = wave * 4 + r4;          /* 0..15 */
    const float MU0     = (float)rowbase * (300.0f / 127.0f) - 150.0f;
    const float MUSTEP  = 16.0f * (300.0f / 127.0f);
    char* genp0 = smat + rowbase * ROWB + i16 * 4;
    char* genp1 = genp0 + BUFB;

    /* mfma role */
    const int ti2 = wave >> 1;
    const int tj2 = wave & 1;

    f32x16 acc[3][2][2];
#pragma unroll
    for (int g = 0; g < 3; ++g)
#pragma unroll
        for (int i = 0; i < 2; ++i)
#pragma unroll
            for (int j = 0; j < 2; ++j)
#pragma unroll
                for (int r = 0; r < 16; ++r) acc[g][i][j][r] = 0.0f;

    const int n0 = chunk * kchunk;

    f32x2 Ra, Ga, Ba, Rb, Gb, Bb;                 /* load ping-pong */
    f32x2 ddrg, ddrb, ddgb, rw2;                  /* current scalars */

    auto issue_ld = [&](int reg, f32x2& R, f32x2& G, f32x2& B) {
        const int n = n0 + reg * 32 + 2 * i16;
        R = *reinterpret_cast<const f32x2*>(Rp + n);
        G = *reinterpret_cast<const f32x2*>(Gp + n);
        B = *reinterpret_cast<const f32x2*>(Bp + n);
    };

    auto scalars = [&](f32x2 R, f32x2 G, f32x2 B) {
        const float C = 34.65735902799726547086f;   /* 50 * ln2 */
        float r0 = fminf(fmaxf(R.x, 0.0f), 1.0f);
        float r1 = fminf(fmaxf(R.y, 0.0f), 1.0f);
        float g0 = fminf(fmaxf(G.x, 0.0f), 1.0f);
        float g1 = fminf(fmaxf(G.y, 0.0f), 1.0f);
        float b0 = fminf(fmaxf(B.x, 0.0f), 1.0f);
        float b1 = fminf(fmaxf(B.y, 0.0f), 1.0f);
        float lr0 = __builtin_amdgcn_logf(r0 + EPSF);
        float lr1 = __builtin_amdgcn_logf(r1 + EPSF);
        float lg0 = __builtin_amdgcn_logf(g0 + EPSF);
        float lg1 = __builtin_amdgcn_logf(g1 + EPSF);
        float lb0 = __builtin_amdgcn_logf(b0 + EPSF);
        float lb1 = __builtin_amdgcn_logf(b1 + EPSF);
        ddrg.x = (lr0 - lg0) * C;  ddrg.y = (lr1 - lg1) * C;
        ddrb.x = (lr0 - lb0) * C;  ddrb.y = (lr1 - lb1) * C;
        ddgb.x = (lg0 - lb0) * C;  ddgb.y = (lg1 - lb1) * C;
        const float s0 = __builtin_fmaf(r0, r0,
                          __builtin_fmaf(g0, g0,
                           __builtin_fmaf(b0, b0, EPSF)));
        const float s1 = __builtin_fmaf(r1, r1,
                          __builtin_fmaf(g1, g1,
                           __builtin_fmaf(b1, b1, EPSF)));
        rw2.x = __builtin_amdgcn_sqrtf(__builtin_amdgcn_sqrtf(s0));
        rw2.y = __builtin_amdgcn_sqrtf(__builtin_amdgcn_sqrtf(s1));
    };

    auto gen = [&](char* bp) {
#pragma unroll
        for (int mat = 0; mat < 3; ++mat) {
            const f32x2 dd = (mat == 0) ? ddrg : (mat == 1) ? ddrb : ddgb;
            float m = MU0;
#pragma unroll
            for (int s = 0; s < 8; ++s) {
                const float ex = dd.x - m, ey = dd.y - m;
                const float tx = __builtin_fmaf(ex, ex, 1.0f);
                const float ty = __builtin_fmaf(ey, ey, 1.0f);
                const float vx = __builtin_amdgcn_rcpf(tx) * rw2.x;
                const float vy = __builtin_amdgcn_rcpf(ty) * rw2.y;
                *reinterpret_cast<unsigned*>(bp + mat * MATB + s * 16 * ROWB)
                    = pk2(vx, vy);
                m += MUSTEP;
            }
        }
    };

    auto do_mfma = [&](const char* mp) {
#pragma unroll
        for (int k0 = 0; k0 < 2; ++k0) {
            const int koff = k0 * 32 + ((lane >> 5) << 4);
            const int r0 = ti2 * 64 + (lane & 31);
            const int c0 = tj2 * 64 + (lane & 31);
            half8 a0 = *reinterpret_cast<const half8*>(mp + 0 * MATB + r0 * ROWB + koff);
            half8 a1 = *reinterpret_cast<const half8*>(mp + 0 * MATB + (r0 + 32) * ROWB + koff);
            half8 p0 = *reinterpret_cast<const half8*>(mp + 1 * MATB + c0 * ROWB + koff);
            half8 p1 = *reinterpret_cast<const half8*>(mp + 1 * MATB + (c0 + 32) * ROWB + koff);
            acc[0][0][0] = __builtin_amdgcn_mfma_f32_32x32x16_f16(a0, p0, acc[0][0][0], 0, 0, 0);
            acc[0][0][1] = __builtin_amdgcn_mfma_f32_32x32x16_f16(a0, p1, acc[0][0][1], 0, 0, 0);
            acc[0][1][0] = __builtin_amdgcn_mfma_f32_32x32x16_f16(a1, p0, acc[0][1][0], 0, 0, 0);
            acc[0][1][1] = __builtin_amdgcn_mfma_f32_32x32x16_f16(a1, p1, acc[0][1][1], 0, 0, 0);
            half8 q0 = *reinterpret_cast<const half8*>(mp + 2 * MATB + c0 * ROWB + koff);
            half8 q1 = *reinterpret_cast<const half8*>(mp + 2 * MATB + (c0 + 32) * ROWB + koff);
            acc[1][0][0] = __builtin_amdgcn_mfma_f32_32x32x16_f16(a0, q0, acc[1][0][0], 0, 0, 0);
            acc[1][0][1] = __builtin_amdgcn_mfma_f32_32x32x16_f16(a0, q1, acc[1][0][1], 0, 0, 0);
            acc[1][1][0] = __builtin_amdgcn_mfma_f32_32x32x16_f16(a1, q0, acc[1][1][0], 0, 0, 0);
            acc[1][1][1] = __builtin_amdgcn_mfma_f32_32x32x16_f16(a1, q1, acc[1][1][1], 0, 0, 0);
            half8 bb0 = *reinterpret_cast<const half8*>(mp + 1 * MATB + r0 * ROWB + koff);
            half8 bb1 = *reinterpret_cast<const half8*>(mp + 1 * MATB + (r0 + 32) * ROWB + koff);
            acc[2][0][0] = __builtin_amdgcn_mfma_f32_32x32x16_f16(bb0, q0, acc[2][0][0], 0, 0, 0);
            acc[2][0][1] = __builtin_amdgcn_mfma_f32_32x32x16_f16(bb0, q1, acc[2][0][1], 0, 0, 0);
            acc[2][1][0] = __builtin_amdgcn_mfma_f32_32x32x16_f16(bb1, q0, acc[2][1][0], 0, 0, 0);
            acc[2][1][1] = __builtin_amdgcn_mfma_f32_32x32x16_f16(bb1, q1, acc[2][1][1], 0, 0, 0);
        }
    };

    /* prologue: gen region 0 into buf0 */
    issue_ld(0, Ra, Ga, Ba);
    scalars(Ra, Ga, Ba);
    gen(genp0);
    issue_ld(1, Rb, Gb, Bb);
    __syncthreads();

    for (int rg = 0; rg < nreg; rg += 2) {
        /* body A: MFMA reg rg (buf0) || gen reg rg+1 -> buf1 */
        scalars(Rb, Gb, Bb);
        issue_ld(min(rg + 2, nreg - 1), Ra, Ga, Ba);
        gen(genp1);
        do_mfma(smat);
        __syncthreads();
        /* body B: MFMA reg rg+1 (buf1) || gen reg rg+2 -> buf0 */
        scalars(Ra, Ga, Ba);
        issue_ld(min(rg + 3, nreg - 1), Rb, Gb, Bb);
        if (rg + 2 < nreg) gen(genp0);
        do_mfma(smat + BUFB);
        __syncthreads();
    }

    /* ---- epilogue: C/D layout col=lane&31, row=(r&3)+8*(r>>2)+4*(lane>>5) */
    float* pb0 = parts + (size_t)blockIdx.x * PPB;
#pragma unroll
    for (int g = 0; g < 3; ++g) {
        float* pp = pb0 + g * (HB * HB);
#pragma unroll
        for (int i2 = 0; i2 < 2; ++i2)
#pragma unroll
            for (int j2 = 0; j2 < 2; ++j2) {
                const int ub = (ti2 * 2 + i2) * 32 + 4 * (lane >> 5);
                const int vc = (tj2 * 2 + j2) * 32 + (lane & 31);
#pragma unroll
                for (int r = 0; r < 16; ++r) {
                    const int urow = ub + (r & 3) + 8 * (r >> 2);
                    pp[urow * HB + vc] = acc[g][i2][j2][r];
                }
            }
    }
}

/* ------- kernel 2: reduce per-chunk partials + fused norm sums -------- */
__global__ __launch_bounds__(256) void reduce_norms(
    const float* __restrict__ parts, float* __restrict__ hist,
    float* __restrict__ norms, int nchunk)
{
    const int i    = blockIdx.x * 256 + threadIdx.x;  /* over 24*16384 */
    const int comb = i >> 14;            /* ib*3 + g  (uniform per block) */
    const int off  = i & 16383;
    const int ib   = comb / 3;
    const int g    = comb % 3;
    const float* p = parts + (size_t)(ib * nchunk) * PPB + g * (HB * HB) + off;
    float s = 0.0f;
    for (int k = 0; k < nchunk; ++k) s += p[(size_t)k * PPB];
    hist[i] = s;
    /* block partial sum -> norms[ib] (all threads in block share ib) */
    for (int o = 32; o > 0; o >>= 1) s += __shfl_down(s, o, 64);
    __shared__ float wsum[4];
    if ((threadIdx.x & 63) == 0) wsum[threadIdx.x >> 6] = s;
    __syncthreads();
    if (threadIdx.x == 0)
        atomicAdd(&norms[ib], wsum[0] + wsum[1] + wsum[2] + wsum[3]);
}

/* ---------------- kernel 3: Hellinger sum ----------------------------- */
__global__ __launch_bounds__(256) void loss_k(
    const float* __restrict__ hist, const float* __restrict__ norms,
    float* __restrict__ acc)
{
    const int i  = blockIdx.x * 256 + threadIdx.x;  /* 0..196608, exact grid */
    const int bb = i / (3 * HB * HB);
    const float rp = __builtin_amdgcn_rcpf(norms[bb] + EPSF);
    const float rt = __builtin_amdgcn_rcpf(norms[4 + bb] + EPSF);
    const float p  = hist[i];
    const float tt = hist[12 * HB * HB + i];
    const float d  = __builtin_amdgcn_sqrtf(tt * rt)
                   - __builtin_amdgcn_sqrtf(p * rp);
    float s = d * d;
    for (int o = 32; o > 0; o >>= 1) s += __shfl_down(s, o, 64);
    __shared__ float wsum[4];
    if ((threadIdx.x & 63) == 0) wsum[threadIdx.x >> 6] = s;
    __syncthreads();
    if (threadIdx.x == 0) atomicAdd(acc, wsum[0] + wsum[1] + wsum[2] + wsum[3]);
}

/* ---------------- kernel 4: final scalar ------------------------------ */
__global__ void final_k(const float* __restrict__ acc, float* __restrict__ out)
{
    out[0] = __builtin_amdgcn_sqrtf(acc[0]) * 0.70710678118654752440f * 0.25f;
}

extern "C" void kernel_launch(void* const* d_in, const int* in_sizes, int n_in,
                              void* d_out, int out_size, void* d_ws, size_t ws_size,
                              hipStream_t stream)
{
    const float* pred = (const float*)d_in[0];
    const float* tgt  = (const float*)d_in[1];
    float* ws  = (float*)d_ws;
    float* out = (float*)d_out;

    float* hist  = ws;                /* 24*16384 = 393216 floats          */
    float* norms = ws + 393216;       /* 8 floats                          */
    float* acc   = ws + 393224;       /* 1 float                           */
    float* parts = ws + 393232;       /* 8*nchunk*PPB floats               */

    /* pick the largest chunk count whose parts buffer fits the workspace */
    int nchunk = 64;
    for (;;) {
        const size_t need =
            (393232 + (size_t)8 * nchunk * PPB) * sizeof(float);
        if (need <= ws_size || nchunk == 1) break;
        nchunk >>= (nchunk == 64) ? 1 : 2;   /* 64 -> 32 -> 8 -> 2 -> 1 */
    }

    (void)hipMemsetAsync(norms, 0, 9 * sizeof(float), stream);  /* norms+acc */

    hist_mfma<<<8 * nchunk, 256, 0, stream>>>(pred, tgt, parts, nchunk);
    reduce_norms<<<NCOMB * HB * HB / 256, 256, 0, stream>>>(parts, hist,
                                                            norms, nchunk);
    loss_k<<<(4 * 3 * HB * HB) / 256, 256, 0, stream>>>(hist, norms, acc);
    final_k<<<1, 1, 0, stream>>>(acc, out);
}